// Round 1
// baseline (5222.105 us; speedup 1.0000x reference)
//
#include <hip/hip_runtime.h>
#include <hip/hip_bf16.h>

// Problem constants (from reference)
#define BB   256
#define SS   100
#define DIN  64
#define DD   256
#define HH   8
#define LL   6
#define DFF  1024
#define DKK  32
#define MM   (BB*SS)          // 25600 rows
#define INV_SCALE 0.17677669529663687f   // 1/sqrt(32)

// ---------------------------------------------------------------------------
// PE init: pe[s][c] = sin/cos(s * exp(-2*floor(c/2) * ln(10000)/D))
// ---------------------------------------------------------------------------
__global__ void pe_init_kernel(float* __restrict__ pe) {
    int i = blockIdx.x * blockDim.x + threadIdx.x;
    if (i >= SS * DD) return;
    int s = i >> 8;          // /256
    int c = i & 255;
    int ce = c & ~1;
    double div = exp((double)ce * -0.03597789207803197);  // -ln(10000)/256
    double ang = (double)s * div;
    pe[i] = (float)((c & 1) ? cos(ang) : sin(ang));
}

// ---------------------------------------------------------------------------
// Tiled fp32 GEMM: C[M,N] = epi(A[M,K] @ W[K,N] + bias[N])
// EPI: 0 = bias only, 1 = bias+relu, 2 = bias + PE (input projection, N==256)
// BM=BN=64, BK=16, 256 threads, 4x4 microtile.
// ---------------------------------------------------------------------------
#define BM 64
#define BN 64
#define BK 16

template <int EPI>
__global__ __launch_bounds__(256)
void gemm_kernel(const float* __restrict__ A, const float* __restrict__ W,
                 const float* __restrict__ bias, const float* __restrict__ pe,
                 float* __restrict__ C, int M, int N, int K) {
    __shared__ float As[BK][BM + 4];
    __shared__ float Bs[BK][BN + 4];

    const int t  = threadIdx.x;
    const int bm = blockIdx.x * BM;
    const int bn = blockIdx.y * BN;
    const int tx = t & 15;
    const int ty = t >> 4;

    // staging indices
    const int a_r = t >> 2;          // 0..63 row in A tile
    const int a_c = (t & 3) * 4;     // 0,4,8,12 k-offset
    const int b_r = t >> 4;          // 0..15 k-row in W tile
    const int b_c = (t & 15) * 4;    // 0..60 n-offset

    float acc[4][4] = {};

    for (int k0 = 0; k0 < K; k0 += BK) {
        float4 av = *(const float4*)&A[(bm + a_r) * K + k0 + a_c];
        As[a_c + 0][a_r] = av.x;
        As[a_c + 1][a_r] = av.y;
        As[a_c + 2][a_r] = av.z;
        As[a_c + 3][a_r] = av.w;
        float4 wv = *(const float4*)&W[(k0 + b_r) * N + bn + b_c];
        *(float4*)&Bs[b_r][b_c] = wv;
        __syncthreads();

#pragma unroll
        for (int kk = 0; kk < BK; ++kk) {
            float4 a = *(const float4*)&As[kk][ty * 4];
            float4 bv = *(const float4*)&Bs[kk][tx * 4];
            acc[0][0] = fmaf(a.x, bv.x, acc[0][0]);
            acc[0][1] = fmaf(a.x, bv.y, acc[0][1]);
            acc[0][2] = fmaf(a.x, bv.z, acc[0][2]);
            acc[0][3] = fmaf(a.x, bv.w, acc[0][3]);
            acc[1][0] = fmaf(a.y, bv.x, acc[1][0]);
            acc[1][1] = fmaf(a.y, bv.y, acc[1][1]);
            acc[1][2] = fmaf(a.y, bv.z, acc[1][2]);
            acc[1][3] = fmaf(a.y, bv.w, acc[1][3]);
            acc[2][0] = fmaf(a.z, bv.x, acc[2][0]);
            acc[2][1] = fmaf(a.z, bv.y, acc[2][1]);
            acc[2][2] = fmaf(a.z, bv.z, acc[2][2]);
            acc[2][3] = fmaf(a.z, bv.w, acc[2][3]);
            acc[3][0] = fmaf(a.w, bv.x, acc[3][0]);
            acc[3][1] = fmaf(a.w, bv.y, acc[3][1]);
            acc[3][2] = fmaf(a.w, bv.z, acc[3][2]);
            acc[3][3] = fmaf(a.w, bv.w, acc[3][3]);
        }
        __syncthreads();
    }

    const int col0 = bn + tx * 4;
    const float4 bfv = *(const float4*)&bias[col0];
#pragma unroll
    for (int i = 0; i < 4; ++i) {
        int row = bm + ty * 4 + i;
        float4 r;
        r.x = acc[i][0] + bfv.x;
        r.y = acc[i][1] + bfv.y;
        r.z = acc[i][2] + bfv.z;
        r.w = acc[i][3] + bfv.w;
        if (EPI == 1) {
            r.x = fmaxf(r.x, 0.f); r.y = fmaxf(r.y, 0.f);
            r.z = fmaxf(r.z, 0.f); r.w = fmaxf(r.w, 0.f);
        }
        if (EPI == 2) {
            int s = row % SS;
            const float4 pv = *(const float4*)&pe[s * DD + col0];
            r.x += pv.x; r.y += pv.y; r.z += pv.z; r.w += pv.w;
        }
        *(float4*)&C[row * N + col0] = r;
    }
}

// ---------------------------------------------------------------------------
// Residual add + LayerNorm over D=256. One block per row, 256 threads.
// out = LN(h + (p ? p : 0)) * g + be.  Safe in-place (out == h).
// ---------------------------------------------------------------------------
__global__ __launch_bounds__(256)
void add_ln_kernel(const float* __restrict__ h, const float* __restrict__ p,
                   const float* __restrict__ g, const float* __restrict__ be,
                   float* __restrict__ out) {
    const int row = blockIdx.x;
    const int c = threadIdx.x;
    const int idx = row * DD + c;
    float x = h[idx];
    if (p) x += p[idx];

    float s1 = x, s2 = x * x;
#pragma unroll
    for (int o = 32; o > 0; o >>= 1) {
        s1 += __shfl_down(s1, o);
        s2 += __shfl_down(s2, o);
    }
    __shared__ float w1[4], w2[4];
    __shared__ float mean_s, rstd_s;
    const int wid = c >> 6, lane = c & 63;
    if (lane == 0) { w1[wid] = s1; w2[wid] = s2; }
    __syncthreads();
    if (c == 0) {
        float t1 = w1[0] + w1[1] + w1[2] + w1[3];
        float t2 = w2[0] + w2[1] + w2[2] + w2[3];
        float m = t1 * (1.0f / DD);
        float v = t2 * (1.0f / DD) - m * m;
        mean_s = m;
        rstd_s = rsqrtf(v + 1e-5f);
    }
    __syncthreads();
    out[idx] = (x - mean_s) * rstd_s * g[c] + be[c];
}

// ---------------------------------------------------------------------------
// Attention: one block per (b, head). Q,K,V staged in LDS (padded +1 to kill
// the stride-32 bank conflict), scores in 50-row chunks (LDS <= 64 KB).
// ---------------------------------------------------------------------------
__global__ __launch_bounds__(256)
void attn_kernel(const float* __restrict__ q, const float* __restrict__ k,
                 const float* __restrict__ v, float* __restrict__ o) {
    const int bh = blockIdx.x;
    const int b = bh >> 3;       // / H
    const int hh = bh & 7;       // % H
    __shared__ float Qs[SS][DKK + 1];
    __shared__ float Ks[SS][DKK + 1];
    __shared__ float Vs[SS][DKK + 1];
    __shared__ float Sc[50][SS + 4];
    const int t = threadIdx.x;
    const int base = (b * SS * HH + hh) * DKK;   // element offset of (b, s=0, hh, d=0)

    for (int i = t; i < SS * DKK; i += 256) {
        int s = i >> 5, d = i & 31;
        int gi = base + s * (HH * DKK) + d;
        Qs[s][d] = q[gi];
        Ks[s][d] = k[gi];
        Vs[s][d] = v[gi];
    }
    __syncthreads();

    for (int cch = 0; cch < 2; ++cch) {
        const int q0 = cch * 50;
        // scores for 50 q-rows x 100 k-cols
        for (int e = t; e < 50 * SS; e += 256) {
            int qr = e / SS, kc = e % SS;
            float acc = 0.f;
#pragma unroll
            for (int d = 0; d < DKK; ++d)
                acc = fmaf(Qs[q0 + qr][d], Ks[kc][d], acc);
            Sc[qr][kc] = acc * INV_SCALE;
        }
        __syncthreads();
        // softmax per row (threads 0..49)
        if (t < 50) {
            float m = -1e30f;
#pragma unroll 4
            for (int j = 0; j < SS; ++j) m = fmaxf(m, Sc[t][j]);
            float sum = 0.f;
#pragma unroll 4
            for (int j = 0; j < SS; ++j) {
                float e2 = expf(Sc[t][j] - m);
                Sc[t][j] = e2;
                sum += e2;
            }
            float inv = 1.0f / sum;
#pragma unroll 4
            for (int j = 0; j < SS; ++j) Sc[t][j] *= inv;
        }
        __syncthreads();
        // O = P @ V : 50x32 outputs
        for (int e = t; e < 50 * DKK; e += 256) {
            int qr = e >> 5, d = e & 31;
            float acc = 0.f;
#pragma unroll 4
            for (int kk = 0; kk < SS; ++kk)
                acc = fmaf(Sc[qr][kk], Vs[kk][d], acc);
            o[base + (q0 + qr) * (HH * DKK) + d] = acc;
        }
        __syncthreads();
    }
}

// ---------------------------------------------------------------------------
// Output heads: one block per batch element, 128 threads.
// out layout: action[256] | regime[768] | conf[256] | vol[256] | hf[65536]
// ---------------------------------------------------------------------------
__global__ __launch_bounds__(128)
void heads_kernel(const float* __restrict__ h,
                  const float* __restrict__ Wr1, const float* __restrict__ br1,
                  const float* __restrict__ Wr2, const float* __restrict__ br2,
                  const float* __restrict__ Wa1, const float* __restrict__ ba1,
                  const float* __restrict__ Wa2, const float* __restrict__ ba2,
                  const float* __restrict__ Wa3, const float* __restrict__ ba3,
                  const float* __restrict__ Wc1, const float* __restrict__ bc1,
                  const float* __restrict__ Wc2, const float* __restrict__ bc2,
                  const float* __restrict__ Wv1, const float* __restrict__ bv1,
                  const float* __restrict__ Wv2, const float* __restrict__ bv2,
                  float* __restrict__ out) {
    const int b = blockIdx.x, t = threadIdx.x;
    __shared__ float hf[DD];
    __shared__ float t1[128];
    __shared__ float t2[64];
    __shared__ float lg[3];
    const int hbase = (b * SS + (SS - 1)) * DD;
    hf[t]       = h[hbase + t];
    hf[t + 128] = h[hbase + t + 128];
    out[1536 + b * DD + t]       = hf[t];
    out[1536 + b * DD + t + 128] = hf[t + 128];
    __syncthreads();

    // regime: relu(hf@Wr1+br1) -> softmax(.@Wr2+br2)
    {
        float acc = br1[t];
        for (int k2 = 0; k2 < DD; ++k2) acc = fmaf(hf[k2], Wr1[k2 * 128 + t], acc);
        t1[t] = fmaxf(acc, 0.f);
    }
    __syncthreads();
    if (t < 3) {
        float a = br2[t];
        for (int k2 = 0; k2 < 128; ++k2) a = fmaf(t1[k2], Wr2[k2 * 3 + t], a);
        lg[t] = a;
    }
    __syncthreads();
    if (t == 0) {
        float m = fmaxf(lg[0], fmaxf(lg[1], lg[2]));
        float e0 = expf(lg[0] - m), e1 = expf(lg[1] - m), e2 = expf(lg[2] - m);
        float inv = 1.0f / (e0 + e1 + e2);
        out[256 + b * 3 + 0] = e0 * inv;
        out[256 + b * 3 + 1] = e1 * inv;
        out[256 + b * 3 + 2] = e2 * inv;
    }
    // action: relu(hf@Wa1) -> relu(@Wa2) -> tanh(@Wa3)
    {
        float acc = ba1[t];
        for (int k2 = 0; k2 < DD; ++k2) acc = fmaf(hf[k2], Wa1[k2 * 128 + t], acc);
        t1[t] = fmaxf(acc, 0.f);
    }
    __syncthreads();
    if (t < 64) {
        float acc = ba2[t];
        for (int k2 = 0; k2 < 128; ++k2) acc = fmaf(t1[k2], Wa2[k2 * 64 + t], acc);
        t2[t] = fmaxf(acc, 0.f);
    }
    __syncthreads();
    if (t == 0) {
        float acc = ba3[0];
        for (int k2 = 0; k2 < 64; ++k2) acc = fmaf(t2[k2], Wa3[k2], acc);
        out[b] = tanhf(acc);
    }
    __syncthreads();
    // confidence: relu(hf@Wc1) -> sigmoid(@Wc2)
    if (t < 64) {
        float acc = bc1[t];
        for (int k2 = 0; k2 < DD; ++k2) acc = fmaf(hf[k2], Wc1[k2 * 64 + t], acc);
        t2[t] = fmaxf(acc, 0.f);
    }
    __syncthreads();
    if (t == 0) {
        float acc = bc2[0];
        for (int k2 = 0; k2 < 64; ++k2) acc = fmaf(t2[k2], Wc2[k2], acc);
        out[1024 + b] = 1.0f / (1.0f + expf(-acc));
    }
    __syncthreads();
    // volatility: relu(hf@Wv1) -> relu(@Wv2)
    if (t < 64) {
        float acc = bv1[t];
        for (int k2 = 0; k2 < DD; ++k2) acc = fmaf(hf[k2], Wv1[k2 * 64 + t], acc);
        t2[t] = fmaxf(acc, 0.f);
    }
    __syncthreads();
    if (t == 0) {
        float acc = bv2[0];
        for (int k2 = 0; k2 < 64; ++k2) acc = fmaf(t2[k2], Wv2[k2], acc);
        out[1280 + b] = fmaxf(acc, 0.f);
    }
}

// ---------------------------------------------------------------------------
// Launch
// ---------------------------------------------------------------------------
extern "C" void kernel_launch(void* const* d_in, const int* in_sizes, int n_in,
                              void* d_out, int out_size, void* d_ws, size_t ws_size,
                              hipStream_t stream) {
    const float* x    = (const float*)d_in[0];
    const float* W_in = (const float*)d_in[1];
    const float* b_in = (const float*)d_in[2];
    const float* Wq   = (const float*)d_in[3];
    const float* bq   = (const float*)d_in[4];
    const float* Wk   = (const float*)d_in[5];
    const float* bk   = (const float*)d_in[6];
    const float* Wv   = (const float*)d_in[7];
    const float* bv   = (const float*)d_in[8];
    const float* Wo   = (const float*)d_in[9];
    const float* bo   = (const float*)d_in[10];
    const float* g1   = (const float*)d_in[11];
    const float* be1  = (const float*)d_in[12];
    const float* W1   = (const float*)d_in[13];
    const float* b1   = (const float*)d_in[14];
    const float* W2   = (const float*)d_in[15];
    const float* b2   = (const float*)d_in[16];
    const float* g2   = (const float*)d_in[17];
    const float* be2  = (const float*)d_in[18];
    const float* lnf_g = (const float*)d_in[19];
    const float* lnf_b = (const float*)d_in[20];
    const float* Wr1  = (const float*)d_in[21];
    const float* br1  = (const float*)d_in[22];
    const float* Wr2  = (const float*)d_in[23];
    const float* br2  = (const float*)d_in[24];
    const float* Wa1  = (const float*)d_in[25];
    const float* ba1  = (const float*)d_in[26];
    const float* Wa2  = (const float*)d_in[27];
    const float* ba2  = (const float*)d_in[28];
    const float* Wa3  = (const float*)d_in[29];
    const float* ba3  = (const float*)d_in[30];
    const float* Wc1  = (const float*)d_in[31];
    const float* bc1  = (const float*)d_in[32];
    const float* Wc2  = (const float*)d_in[33];
    const float* bc2  = (const float*)d_in[34];
    const float* Wv1  = (const float*)d_in[35];
    const float* bv1  = (const float*)d_in[36];
    const float* Wv2  = (const float*)d_in[37];
    const float* bv2  = (const float*)d_in[38];
    float* out = (float*)d_out;

    // workspace layout (floats)
    float* ws   = (float*)d_ws;
    float* pe   = ws;                       // 25600
    float* h    = pe + SS * DD;             // 6,553,600
    float* qb   = h   + MM * DD;
    float* kb   = qb  + MM * DD;
    float* vb   = kb  + MM * DD;
    float* ao   = vb  + MM * DD;
    float* tmp  = ao  + MM * DD;
    float* ffn1 = tmp + MM * DD;            // 26,214,400

    // PE table
    pe_init_kernel<<<(SS * DD + 255) / 256, 256, 0, stream>>>(pe);

    dim3 gD(MM / BM, DD / BN);    // GEMMs producing N=256
    dim3 gF(MM / BM, DFF / BN);   // GEMM producing N=1024

    // input projection + PE
    gemm_kernel<2><<<gD, 256, 0, stream>>>(x, W_in, b_in, pe, h, MM, DD, DIN);

    for (int l = 0; l < LL; ++l) {
        const float* wq = Wq + l * DD * DD;
        const float* wk = Wk + l * DD * DD;
        const float* wv = Wv + l * DD * DD;
        const float* wo = Wo + l * DD * DD;
        const float* w1 = W1 + l * DD * DFF;
        const float* w2 = W2 + l * DFF * DD;

        gemm_kernel<0><<<gD, 256, 0, stream>>>(h, wq, bq + l * DD, nullptr, qb, MM, DD, DD);
        gemm_kernel<0><<<gD, 256, 0, stream>>>(h, wk, bk + l * DD, nullptr, kb, MM, DD, DD);
        gemm_kernel<0><<<gD, 256, 0, stream>>>(h, wv, bv + l * DD, nullptr, vb, MM, DD, DD);

        attn_kernel<<<BB * HH, 256, 0, stream>>>(qb, kb, vb, ao);

        gemm_kernel<0><<<gD, 256, 0, stream>>>(ao, wo, bo + l * DD, nullptr, tmp, MM, DD, DD);
        add_ln_kernel<<<MM, DD, 0, stream>>>(h, tmp, g1 + l * DD, be1 + l * DD, h);

        gemm_kernel<1><<<gF, 256, 0, stream>>>(h, w1, b1 + l * DFF, nullptr, ffn1, MM, DFF, DD);
        gemm_kernel<0><<<gD, 256, 0, stream>>>(ffn1, w2, b2 + l * DD, nullptr, tmp, MM, DD, DFF);
        add_ln_kernel<<<MM, DD, 0, stream>>>(h, tmp, g2 + l * DD, be2 + l * DD, h);
    }

    // final LN (in place)
    add_ln_kernel<<<MM, DD, 0, stream>>>(h, nullptr, lnf_g, lnf_b, h);

    // heads
    heads_kernel<<<BB, 128, 0, stream>>>(h,
        Wr1, br1, Wr2, br2,
        Wa1, ba1, Wa2, ba2, Wa3, ba3,
        Wc1, bc1, Wc2, bc2,
        Wv1, bv1, Wv2, bv2,
        out);
}

// Round 2
// 1200.338 us; speedup vs baseline: 4.3505x; 4.3505x over previous
//
#include <hip/hip_runtime.h>
#include <hip/hip_bf16.h>

// Problem constants
#define BB   256
#define SS   100
#define DIN  64
#define DD   256
#define HH   8
#define LL   6
#define DFF  1024
#define DKK  32
#define MM   (BB*SS)          // 25600 rows
#define INV_SCALE 0.17677669529663687f   // 1/sqrt(32)

typedef unsigned short u16;
typedef __attribute__((__ext_vector_type__(8))) __bf16 bf16x8;
typedef __attribute__((__ext_vector_type__(4))) float  f32x4;

__device__ __forceinline__ u16 f2bf(float f) {
    unsigned u = __float_as_uint(f);
    u += 0x7FFFu + ((u >> 16) & 1u);      // RNE
    return (u16)(u >> 16);
}

#define MFMA16(a,b,c) __builtin_amdgcn_mfma_f32_16x16x32_bf16((a),(b),(c),0,0,0)

// ---------------------------------------------------------------------------
// PE init
// ---------------------------------------------------------------------------
__global__ void pe_init_kernel(float* __restrict__ pe) {
    int i = blockIdx.x * blockDim.x + threadIdx.x;
    if (i >= SS * DD) return;
    int s = i >> 8;
    int c = i & 255;
    int ce = c & ~1;
    double div = exp((double)ce * -0.03597789207803197);  // -ln(10000)/256
    double ang = (double)s * div;
    pe[i] = (float)((c & 1) ? cos(ang) : sin(ang));
}

// ---------------------------------------------------------------------------
// fp32 -> bf16 elementwise
// ---------------------------------------------------------------------------
__global__ void conv_bf16(const float* __restrict__ in, u16* __restrict__ out, int n) {
    int i = blockIdx.x * 256 + threadIdx.x;
    if (i < n) out[i] = f2bf(in[i]);
}

// ---------------------------------------------------------------------------
// Tiled transpose+convert: in [L][K][N] fp32 -> out [L][N][K] bf16
// grid (K/32, N/32, L), 256 threads (32x8)
// ---------------------------------------------------------------------------
__global__ __launch_bounds__(256)
void transpose_conv(const float* __restrict__ in, u16* __restrict__ out,
                    int K, int N, long outLstride) {
    __shared__ float tile[32][33];
    const int k0 = blockIdx.x * 32, n0 = blockIdx.y * 32, lz = blockIdx.z;
    const int tx = threadIdx.x & 31, ty = threadIdx.x >> 5;
    const float* src = in + (size_t)lz * K * N;
#pragma unroll
    for (int i = 0; i < 4; ++i)
        tile[ty + i*8][tx] = src[(size_t)(k0 + ty + i*8) * N + n0 + tx];
    __syncthreads();
    u16* dst = out + (size_t)lz * outLstride;
#pragma unroll
    for (int i = 0; i < 4; ++i)
        dst[(size_t)(n0 + ty + i*8) * K + k0 + tx] = f2bf(tile[tx][ty + i*8]);
}

// ---------------------------------------------------------------------------
// Pack bq|bk|bv into bqkv[L][768]
// ---------------------------------------------------------------------------
__global__ void pack_bias(const float* __restrict__ bq, const float* __restrict__ bk,
                          const float* __restrict__ bv, float* __restrict__ bqkv) {
    int idx = blockIdx.x * 256 + threadIdx.x;
    if (idx >= LL * 768) return;
    int l = idx / 768, c = idx % 768;
    float v = (c < 256) ? bq[l*256 + c] : (c < 512) ? bk[l*256 + c - 256] : bv[l*256 + c - 512];
    bqkv[idx] = v;
}

// ---------------------------------------------------------------------------
// bf16 MFMA GEMM: C = epi(A[M,K] @ Wt[N,K]^T + bias)
// 128x128 tile, 4 waves (2x2 of 64x64), BK=32, reg-staged LDS, padded stride.
// EPI: 0=bias, 1=bias+relu, 2=bias+PE.  OF32/OBF16 select output buffers.
// ---------------------------------------------------------------------------
#define GBM 128
#define GBN 128
#define GBK 32
#define LDSTR 40   // 32 + 8 pad elems: 80B rows -> <=2-way bank aliasing (free)

template<int EPI, bool OF32, bool OBF16>
__global__ __launch_bounds__(256)
void mfma_gemm(const u16* __restrict__ A, const u16* __restrict__ Wt,
               const float* __restrict__ bias, const float* __restrict__ pe,
               float* __restrict__ Cf, u16* __restrict__ Cb,
               int M, int N, int K) {
    __shared__ u16 As[GBM * LDSTR];
    __shared__ u16 Bs[GBN * LDSTR];
    const int t = threadIdx.x;
    const int w = t >> 6, l = t & 63;
    const int bm = blockIdx.x * GBM, bn = blockIdx.y * GBN;
    const int wr = (w >> 1) * 64, wc = (w & 1) * 64;
    const int lr = l & 15, lk = (l >> 4) * 8, lq = (l >> 4) * 4;

    f32x4 acc[4][4] = {};

    const int r0 = t >> 2;             // rows r0 and r0+64, 16B part p0
    const int p0 = (t & 3) * 8;

    for (int k0 = 0; k0 < K; k0 += GBK) {
        *(uint4*)&As[(r0     ) * LDSTR + p0] = *(const uint4*)&A [(size_t)(bm + r0     ) * K + k0 + p0];
        *(uint4*)&As[(r0 + 64) * LDSTR + p0] = *(const uint4*)&A [(size_t)(bm + r0 + 64) * K + k0 + p0];
        *(uint4*)&Bs[(r0     ) * LDSTR + p0] = *(const uint4*)&Wt[(size_t)(bn + r0     ) * K + k0 + p0];
        *(uint4*)&Bs[(r0 + 64) * LDSTR + p0] = *(const uint4*)&Wt[(size_t)(bn + r0 + 64) * K + k0 + p0];
        __syncthreads();

        bf16x8 af[4], bfr[4];
#pragma unroll
        for (int m = 0; m < 4; ++m) af[m]  = *(const bf16x8*)&As[(wr + m*16 + lr) * LDSTR + lk];
#pragma unroll
        for (int n = 0; n < 4; ++n) bfr[n] = *(const bf16x8*)&Bs[(wc + n*16 + lr) * LDSTR + lk];
#pragma unroll
        for (int m = 0; m < 4; ++m)
#pragma unroll
            for (int n = 0; n < 4; ++n)
                acc[m][n] = MFMA16(af[m], bfr[n], acc[m][n]);
        __syncthreads();
    }

    // epilogue: C/D frag layout col=lane&15, row=(lane>>4)*4+j  [m89/m91]
#pragma unroll
    for (int n = 0; n < 4; ++n) {
        const int col = bn + wc + n*16 + lr;
        const float bv = bias[col];
#pragma unroll
        for (int m = 0; m < 4; ++m) {
#pragma unroll
            for (int j = 0; j < 4; ++j) {
                const int row = bm + wr + m*16 + lq + j;
                float v = acc[m][n][j] + bv;
                if (EPI == 1) v = fmaxf(v, 0.f);
                if (EPI == 2) v += pe[(row % SS) * DD + col];
                if (OF32)  Cf[(size_t)row * N + col] = v;
                if (OBF16) Cb[(size_t)row * N + col] = f2bf(v);
            }
        }
    }
}

// ---------------------------------------------------------------------------
// MFMA attention: one block per (b,h), 4 waves; wave w owns q-rows [32w,32w+32).
// S=Q@K^T via 16x16x32 MFMA (K staged row-major; B^T trick: K-frag == A-frag
// layout). In-register wave-parallel softmax (16-lane shfl_xor groups).
// P->LDS bf16, PV via MFMA with V^T staged in LDS. Rows>=100 zero-padded.
// ---------------------------------------------------------------------------
__global__ __launch_bounds__(256)
void attn_mfma(const u16* __restrict__ qkv, u16* __restrict__ ao) {
    const int b = blockIdx.x >> 3, hh = blockIdx.x & 7;
    const int t = threadIdx.x, w = t >> 6, l = t & 63;
    const int lr = l & 15, lk = (l >> 4) * 8, lq = (l >> 4) * 4;
    __shared__ u16 Qs[128 * 40];
    __shared__ u16 Ks[112 * 40];
    __shared__ u16 Vt[32 * 136];
    __shared__ u16 Ps[4][32 * 136];
    const size_t rbase = (size_t)b * SS * 768;
    const int qc = hh * 32, kc = 256 + hh * 32, vc = 512 + hh * 32;
    const uint4 zz = {0, 0, 0, 0};

    for (int ci = t; ci < 512; ci += 256) {          // Q: 128 rows x 4 chunks
        int r = ci >> 2, p = (ci & 3) * 8;
        uint4 val = (r < SS) ? *(const uint4*)&qkv[rbase + (size_t)r * 768 + qc + p] : zz;
        *(uint4*)&Qs[r * 40 + p] = val;
    }
    for (int ci = t; ci < 448; ci += 256) {          // K: 112 rows
        int r = ci >> 2, p = (ci & 3) * 8;
        uint4 val = (r < SS) ? *(const uint4*)&qkv[rbase + (size_t)r * 768 + kc + p] : zz;
        *(uint4*)&Ks[r * 40 + p] = val;
    }
    for (int i = t; i < 32 * 136; i += 256) {        // V^T[d][s], s-padded to 136
        int d = i / 136, s = i % 136;
        Vt[i] = (s < SS) ? qkv[rbase + (size_t)s * 768 + vc + d] : (u16)0;
    }
    __syncthreads();

    // S = Q K^T  (2 m-frags x 7 n-frags, single K-step K=32)
    f32x4 sacc[2][7] = {};
    bf16x8 qf[2];
#pragma unroll
    for (int m = 0; m < 2; ++m)
        qf[m] = *(const bf16x8*)&Qs[(w*32 + m*16 + lr) * 40 + lk];
#pragma unroll
    for (int n = 0; n < 7; ++n) {
        bf16x8 kf = *(const bf16x8*)&Ks[(n*16 + lr) * 40 + lk];
#pragma unroll
        for (int m = 0; m < 2; ++m) sacc[m][n] = MFMA16(qf[m], kf, sacc[m][n]);
    }

    // softmax per row (row = 32w + 16m + lq + j; cols n*16+lr; col>=100 masked)
#pragma unroll
    for (int m = 0; m < 2; ++m) {
#pragma unroll
        for (int j = 0; j < 4; ++j) {
            float mx = -1e30f;
#pragma unroll
            for (int n = 0; n < 7; ++n) {
                float s = sacc[m][n][j] * INV_SCALE;
                if (n == 6 && lr >= 4) s = -1e30f;   // cols 100..111 invalid
                sacc[m][n][j] = s;
                mx = fmaxf(mx, s);
            }
            mx = fmaxf(mx, __shfl_xor(mx, 1));
            mx = fmaxf(mx, __shfl_xor(mx, 2));
            mx = fmaxf(mx, __shfl_xor(mx, 4));
            mx = fmaxf(mx, __shfl_xor(mx, 8));
            float sum = 0.f;
#pragma unroll
            for (int n = 0; n < 7; ++n) {
                float p = expf(sacc[m][n][j] - mx);
                if (n == 6 && lr >= 4) p = 0.f;
                sacc[m][n][j] = p;
                sum += p;
            }
            sum += __shfl_xor(sum, 1);
            sum += __shfl_xor(sum, 2);
            sum += __shfl_xor(sum, 4);
            sum += __shfl_xor(sum, 8);
            float inv = 1.f / sum;
#pragma unroll
            for (int n = 0; n < 7; ++n) sacc[m][n][j] *= inv;
        }
    }

    // P -> LDS (bf16), wave-private region; zero pad cols 112..135
    u16* myP = &Ps[w][0];
    for (int i = l; i < 32 * 24; i += 64) {
        int r = i / 24, c2 = 112 + i % 24;
        myP[r * 136 + c2] = 0;
    }
#pragma unroll
    for (int m = 0; m < 2; ++m)
#pragma unroll
        for (int n = 0; n < 7; ++n)
#pragma unroll
            for (int j = 0; j < 4; ++j)
                myP[(m*16 + lq + j) * 136 + n*16 + lr] = f2bf(sacc[m][n][j]);

    // O = P @ V  (K padded to 128; P cols >=100 are zero)
    f32x4 oacc[2][2] = {};
#pragma unroll
    for (int ks = 0; ks < 4; ++ks) {
        bf16x8 pf[2], vf[2];
#pragma unroll
        for (int m = 0; m < 2; ++m) pf[m] = *(const bf16x8*)&myP[(m*16 + lr) * 136 + ks*32 + lk];
#pragma unroll
        for (int n = 0; n < 2; ++n) vf[n] = *(const bf16x8*)&Vt [(n*16 + lr) * 136 + ks*32 + lk];
#pragma unroll
        for (int m = 0; m < 2; ++m)
#pragma unroll
            for (int n = 0; n < 2; ++n)
                oacc[m][n] = MFMA16(pf[m], vf[n], oacc[m][n]);
    }
#pragma unroll
    for (int m = 0; m < 2; ++m)
#pragma unroll
        for (int j = 0; j < 4; ++j) {
            int s = w*32 + m*16 + lq + j;
            if (s < SS) {
#pragma unroll
                for (int n = 0; n < 2; ++n)
                    ao[((size_t)(b*SS + s)) * DD + hh*32 + n*16 + lr] = f2bf(oacc[m][n][j]);
            }
        }
}

// ---------------------------------------------------------------------------
// Residual add + LayerNorm (fp32), optional bf16 mirror output.
// ---------------------------------------------------------------------------
__global__ __launch_bounds__(256)
void add_ln_kernel(const float* __restrict__ h, const float* __restrict__ p,
                   const float* __restrict__ g, const float* __restrict__ be,
                   float* __restrict__ out, u16* __restrict__ outb) {
    const int row = blockIdx.x;
    const int c = threadIdx.x;
    const int idx = row * DD + c;
    float x = h[idx];
    if (p) x += p[idx];

    float s1 = x, s2 = x * x;
#pragma unroll
    for (int o = 32; o > 0; o >>= 1) {
        s1 += __shfl_down(s1, o);
        s2 += __shfl_down(s2, o);
    }
    __shared__ float w1[4], w2[4];
    __shared__ float mean_s, rstd_s;
    const int wid = c >> 6, lane = c & 63;
    if (lane == 0) { w1[wid] = s1; w2[wid] = s2; }
    __syncthreads();
    if (c == 0) {
        float t1 = w1[0] + w1[1] + w1[2] + w1[3];
        float t2 = w2[0] + w2[1] + w2[2] + w2[3];
        float m = t1 * (1.0f / DD);
        float v = t2 * (1.0f / DD) - m * m;
        mean_s = m;
        rstd_s = rsqrtf(v + 1e-5f);
    }
    __syncthreads();
    float y = (x - mean_s) * rstd_s * g[c] + be[c];
    out[idx] = y;
    if (outb) outb[idx] = f2bf(y);
}

// ---------------------------------------------------------------------------
// Output heads (unchanged from passing R0)
// ---------------------------------------------------------------------------
__global__ __launch_bounds__(128)
void heads_kernel(const float* __restrict__ h,
                  const float* __restrict__ Wr1, const float* __restrict__ br1,
                  const float* __restrict__ Wr2, const float* __restrict__ br2,
                  const float* __restrict__ Wa1, const float* __restrict__ ba1,
                  const float* __restrict__ Wa2, const float* __restrict__ ba2,
                  const float* __restrict__ Wa3, const float* __restrict__ ba3,
                  const float* __restrict__ Wc1, const float* __restrict__ bc1,
                  const float* __restrict__ Wc2, const float* __restrict__ bc2,
                  const float* __restrict__ Wv1, const float* __restrict__ bv1,
                  const float* __restrict__ Wv2, const float* __restrict__ bv2,
                  float* __restrict__ out) {
    const int b = blockIdx.x, t = threadIdx.x;
    __shared__ float hf[DD];
    __shared__ float t1[128];
    __shared__ float t2[64];
    __shared__ float lg[3];
    const int hbase = (b * SS + (SS - 1)) * DD;
    hf[t]       = h[hbase + t];
    hf[t + 128] = h[hbase + t + 128];
    out[1536 + b * DD + t]       = hf[t];
    out[1536 + b * DD + t + 128] = hf[t + 128];
    __syncthreads();

    {
        float acc = br1[t];
        for (int k2 = 0; k2 < DD; ++k2) acc = fmaf(hf[k2], Wr1[k2 * 128 + t], acc);
        t1[t] = fmaxf(acc, 0.f);
    }
    __syncthreads();
    if (t < 3) {
        float a = br2[t];
        for (int k2 = 0; k2 < 128; ++k2) a = fmaf(t1[k2], Wr2[k2 * 3 + t], a);
        lg[t] = a;
    }
    __syncthreads();
    if (t == 0) {
        float m = fmaxf(lg[0], fmaxf(lg[1], lg[2]));
        float e0 = expf(lg[0] - m), e1 = expf(lg[1] - m), e2 = expf(lg[2] - m);
        float inv = 1.0f / (e0 + e1 + e2);
        out[256 + b * 3 + 0] = e0 * inv;
        out[256 + b * 3 + 1] = e1 * inv;
        out[256 + b * 3 + 2] = e2 * inv;
    }
    {
        float acc = ba1[t];
        for (int k2 = 0; k2 < DD; ++k2) acc = fmaf(hf[k2], Wa1[k2 * 128 + t], acc);
        t1[t] = fmaxf(acc, 0.f);
    }
    __syncthreads();
    if (t < 64) {
        float acc = ba2[t];
        for (int k2 = 0; k2 < 128; ++k2) acc = fmaf(t1[k2], Wa2[k2 * 64 + t], acc);
        t2[t] = fmaxf(acc, 0.f);
    }
    __syncthreads();
    if (t == 0) {
        float acc = ba3[0];
        for (int k2 = 0; k2 < 64; ++k2) acc = fmaf(t2[k2], Wa3[k2], acc);
        out[b] = tanhf(acc);
    }
    __syncthreads();
    if (t < 64) {
        float acc = bc1[t];
        for (int k2 = 0; k2 < DD; ++k2) acc = fmaf(hf[k2], Wc1[k2 * 64 + t], acc);
        t2[t] = fmaxf(acc, 0.f);
    }
    __syncthreads();
    if (t == 0) {
        float acc = bc2[0];
        for (int k2 = 0; k2 < 64; ++k2) acc = fmaf(t2[k2], Wc2[k2], acc);
        out[1024 + b] = 1.0f / (1.0f + expf(-acc));
    }
    __syncthreads();
    if (t < 64) {
        float acc = bv1[t];
        for (int k2 = 0; k2 < DD; ++k2) acc = fmaf(hf[k2], Wv1[k2 * 64 + t], acc);
        t2[t] = fmaxf(acc, 0.f);
    }
    __syncthreads();
    if (t == 0) {
        float acc = bv2[0];
        for (int k2 = 0; k2 < 64; ++k2) acc = fmaf(t2[k2], Wv2[k2], acc);
        out[1280 + b] = fmaxf(acc, 0.f);
    }
}

// ---------------------------------------------------------------------------
// Launch
// ---------------------------------------------------------------------------
extern "C" void kernel_launch(void* const* d_in, const int* in_sizes, int n_in,
                              void* d_out, int out_size, void* d_ws, size_t ws_size,
                              hipStream_t stream) {
    const float* x    = (const float*)d_in[0];
    const float* W_in = (const float*)d_in[1];
    const float* b_in = (const float*)d_in[2];
    const float* Wq   = (const float*)d_in[3];
    const float* bq   = (const float*)d_in[4];
    const float* Wk   = (const float*)d_in[5];
    const float* bk   = (const float*)d_in[6];
    const float* Wv   = (const float*)d_in[7];
    const float* bv   = (const float*)d_in[8];
    const float* Wo   = (const float*)d_in[9];
    const float* bo   = (const float*)d_in[10];
    const float* g1   = (const float*)d_in[11];
    const float* be1  = (const float*)d_in[12];
    const float* W1   = (const float*)d_in[13];
    const float* b1   = (const float*)d_in[14];
    const float* W2   = (const float*)d_in[15];
    const float* b2   = (const float*)d_in[16];
    const float* g2   = (const float*)d_in[17];
    const float* be2  = (const float*)d_in[18];
    const float* lnf_g = (const float*)d_in[19];
    const float* lnf_b = (const float*)d_in[20];
    const float* Wr1  = (const float*)d_in[21];
    const float* br1  = (const float*)d_in[22];
    const float* Wr2  = (const float*)d_in[23];
    const float* br2  = (const float*)d_in[24];
    const float* Wa1  = (const float*)d_in[25];
    const float* ba1  = (const float*)d_in[26];
    const float* Wa2  = (const float*)d_in[27];
    const float* ba2  = (const float*)d_in[28];
    const float* Wa3  = (const float*)d_in[29];
    const float* ba3  = (const float*)d_in[30];
    const float* Wc1  = (const float*)d_in[31];
    const float* bc1  = (const float*)d_in[32];
    const float* Wc2  = (const float*)d_in[33];
    const float* bc2  = (const float*)d_in[34];
    const float* Wv1  = (const float*)d_in[35];
    const float* bv1  = (const float*)d_in[36];
    const float* Wv2  = (const float*)d_in[37];
    const float* bv2  = (const float*)d_in[38];
    float* out = (float*)d_out;

    // workspace layout
    char* w8 = (char*)d_ws;
    float* pe   = (float*)w8;  w8 += (size_t)SS * DD * 4;
    float* h    = (float*)w8;  w8 += (size_t)MM * DD * 4;
    float* tmp  = (float*)w8;  w8 += (size_t)MM * DD * 4;
    u16*   hb   = (u16*)w8;    w8 += (size_t)MM * DD * 2;
    u16*   xb   = (u16*)w8;    w8 += (size_t)MM * DIN * 2;
    u16*   qkvb = (u16*)w8;    w8 += (size_t)MM * 768 * 2;
    u16*   ao   = (u16*)w8;    w8 += (size_t)MM * DD * 2;
    u16*   ffn1b= (u16*)w8;    w8 += (size_t)MM * DFF * 2;
    u16*   WinT = (u16*)w8;    w8 += (size_t)DIN * DD * 2;
    u16*   WqkvT= (u16*)w8;    w8 += (size_t)LL * 768 * DD * 2;
    u16*   WoT  = (u16*)w8;    w8 += (size_t)LL * DD * DD * 2;
    u16*   W1T  = (u16*)w8;    w8 += (size_t)LL * DFF * DD * 2;
    u16*   W2T  = (u16*)w8;    w8 += (size_t)LL * DD * DFF * 2;
    float* bqkv = (float*)w8;  w8 += (size_t)LL * 768 * 4;

    // prep
    pe_init_kernel<<<(SS * DD + 255) / 256, 256, 0, stream>>>(pe);
    conv_bf16<<<(MM * DIN + 255) / 256, 256, 0, stream>>>(x, xb, MM * DIN);
    transpose_conv<<<dim3(DIN/32, DD/32, 1), 256, 0, stream>>>(W_in, WinT, DIN, DD, (long)DIN * DD);
    transpose_conv<<<dim3(8, 8, 6),  256, 0, stream>>>(Wq, WqkvT,             DD, DD, 768L * DD);
    transpose_conv<<<dim3(8, 8, 6),  256, 0, stream>>>(Wk, WqkvT + DD*DD,     DD, DD, 768L * DD);
    transpose_conv<<<dim3(8, 8, 6),  256, 0, stream>>>(Wv, WqkvT + 2*DD*DD,   DD, DD, 768L * DD);
    transpose_conv<<<dim3(8, 8, 6),  256, 0, stream>>>(Wo, WoT, DD, DD, (long)DD * DD);
    transpose_conv<<<dim3(8, 32, 6), 256, 0, stream>>>(W1, W1T, DD, DFF, (long)DD * DFF);
    transpose_conv<<<dim3(32, 8, 6), 256, 0, stream>>>(W2, W2T, DFF, DD, (long)DD * DFF);
    pack_bias<<<(LL * 768 + 255) / 256, 256, 0, stream>>>(bq, bk, bv, bqkv);

    // input projection + PE  (h fp32 + hb bf16)
    mfma_gemm<2, true, true><<<dim3(MM/128, DD/128), 256, 0, stream>>>(
        xb, WinT, b_in, pe, h, hb, MM, DD, DIN);

    for (int l = 0; l < LL; ++l) {
        mfma_gemm<0, false, true><<<dim3(MM/128, 768/128), 256, 0, stream>>>(
            hb, WqkvT + (size_t)l*768*DD, bqkv + l*768, nullptr, nullptr, qkvb, MM, 768, DD);
        attn_mfma<<<BB * HH, 256, 0, stream>>>(qkvb, ao);
        mfma_gemm<0, true, false><<<dim3(MM/128, DD/128), 256, 0, stream>>>(
            ao, WoT + (size_t)l*DD*DD, bo + l*DD, nullptr, tmp, nullptr, MM, DD, DD);
        add_ln_kernel<<<MM, DD, 0, stream>>>(h, tmp, g1 + l*DD, be1 + l*DD, h, hb);
        mfma_gemm<1, false, true><<<dim3(MM/128, DFF/128), 256, 0, stream>>>(
            hb, W1T + (size_t)l*DFF*DD, b1 + l*DFF, nullptr, nullptr, ffn1b, MM, DFF, DD);
        mfma_gemm<0, true, false><<<dim3(MM/128, DD/128), 256, 0, stream>>>(
            ffn1b, W2T + (size_t)l*DD*DFF, b2 + l*DD, nullptr, tmp, nullptr, MM, DD, DFF);
        add_ln_kernel<<<MM, DD, 0, stream>>>(h, tmp, g2 + l*DD, be2 + l*DD, h, hb);
    }

    add_ln_kernel<<<MM, DD, 0, stream>>>(h, nullptr, lnf_g, lnf_b, h, nullptr);

    heads_kernel<<<BB, 128, 0, stream>>>(h,
        Wr1, br1, Wr2, br2,
        Wa1, ba1, Wa2, ba2, Wa3, ba3,
        Wc1, bc1, Wc2, bc2,
        Wv1, bv1, Wv2, bv2,
        out);
}

// Round 3
// 964.992 us; speedup vs baseline: 5.4116x; 1.2439x over previous
//
#include <hip/hip_runtime.h>
#include <hip/hip_bf16.h>

// Problem constants
#define BB   256
#define SS   100
#define DIN  64
#define DD   256
#define HH   8
#define LL   6
#define DFF  1024
#define MM   (BB*SS)          // 25600 rows
#define INV_SCALE 0.17677669529663687f   // 1/sqrt(32)

typedef unsigned short u16;
typedef __attribute__((__ext_vector_type__(8))) __bf16 bf16x8;
typedef __attribute__((__ext_vector_type__(8))) unsigned short u16x8;
typedef __attribute__((__ext_vector_type__(4))) float  f32x4;

__device__ __forceinline__ u16 f2bf(float f) {
    unsigned u = __float_as_uint(f);
    u += 0x7FFFu + ((u >> 16) & 1u);      // RNE
    return (u16)(u >> 16);
}

#define MFMA16(a,b,c) __builtin_amdgcn_mfma_f32_16x16x32_bf16((a),(b),(c),0,0,0)

// async global->LDS, 16B per lane. dest = wave-uniform base + lane*16.
#if defined(__has_builtin)
#if __has_builtin(__builtin_amdgcn_global_load_lds)
#define HAVE_GLDS 1
#endif
#endif

#ifdef HAVE_GLDS
typedef __attribute__((address_space(1))) const void gas_void;
typedef __attribute__((address_space(3))) void las_void;
__device__ __forceinline__ void gload16(const u16* g, u16* l) {
    __builtin_amdgcn_global_load_lds((gas_void*)g, (las_void*)l, 16, 0, 0);
}
#else
// fallback: reg-staged (lane l mirrors the wave-uniform-base + l*16 layout)
__device__ __forceinline__ void gload16(const u16* g, u16* l) {
    const int lane = threadIdx.x & 63;
    *(uint4*)((char*)l + lane * 16) = *(const uint4*)g;
}
#endif

// ---------------------------------------------------------------------------
// PE init
// ---------------------------------------------------------------------------
__global__ void pe_init_kernel(float* __restrict__ pe) {
    int i = blockIdx.x * blockDim.x + threadIdx.x;
    if (i >= SS * DD) return;
    int s = i >> 8;
    int c = i & 255;
    int ce = c & ~1;
    double div = exp((double)ce * -0.03597789207803197);  // -ln(10000)/256
    double ang = (double)s * div;
    pe[i] = (float)((c & 1) ? cos(ang) : sin(ang));
}

// ---------------------------------------------------------------------------
// fp32 -> bf16 elementwise
// ---------------------------------------------------------------------------
__global__ void conv_bf16(const float* __restrict__ in, u16* __restrict__ out, int n) {
    int i = blockIdx.x * 256 + threadIdx.x;
    if (i < n) out[i] = f2bf(in[i]);
}

// ---------------------------------------------------------------------------
// Tiled transpose+convert: in [L][K][N] fp32 -> out [L][N][K] bf16
// ---------------------------------------------------------------------------
__global__ __launch_bounds__(256)
void transpose_conv(const float* __restrict__ in, u16* __restrict__ out,
                    int K, int N, long outLstride) {
    __shared__ float tile[32][33];
    const int k0 = blockIdx.x * 32, n0 = blockIdx.y * 32, lz = blockIdx.z;
    const int tx = threadIdx.x & 31, ty = threadIdx.x >> 5;
    const float* src = in + (size_t)lz * K * N;
#pragma unroll
    for (int i = 0; i < 4; ++i)
        tile[ty + i*8][tx] = src[(size_t)(k0 + ty + i*8) * N + n0 + tx];
    __syncthreads();
    u16* dst = out + (size_t)lz * outLstride;
#pragma unroll
    for (int i = 0; i < 4; ++i)
        dst[(size_t)(n0 + ty + i*8) * K + k0 + tx] = f2bf(tile[tx][ty + i*8]);
}

// ---------------------------------------------------------------------------
// Pack bq|bk|bv into bqkv[L][768]
// ---------------------------------------------------------------------------
__global__ void pack_bias(const float* __restrict__ bq, const float* __restrict__ bk,
                          const float* __restrict__ bv, float* __restrict__ bqkv) {
    int idx = blockIdx.x * 256 + threadIdx.x;
    if (idx >= LL * 768) return;
    int l = idx / 768, c = idx % 768;
    float v = (c < 256) ? bq[l*256 + c] : (c < 512) ? bk[l*256 + c - 256] : bv[l*256 + c - 512];
    bqkv[idx] = v;
}

// ---------------------------------------------------------------------------
// m97-structure bf16 MFMA GEMM: C = epi(A[M,K] @ Wt[N,K]^T + bias)
// 128x128 tile, 2x2 waves (64x64 each), BK=32, linear LDS + global_load_lds.
// EPI: 0=bias, 1=bias+relu, 2=bias+PE.
// ---------------------------------------------------------------------------
template<int EPI, bool OF32, bool OBF16>
__global__ __launch_bounds__(256)
void mfma_gemm(const u16* __restrict__ A, const u16* __restrict__ Wt,
               const float* __restrict__ bias, const float* __restrict__ pe,
               float* __restrict__ Cf, u16* __restrict__ Cb,
               int M, int N, int K) {
    __shared__ u16 As[128 * 32];
    __shared__ u16 Bs[128 * 32];
    const int t = threadIdx.x, w = t >> 6, l = t & 63;
    const int bm = blockIdx.x * 128, bn = blockIdx.y * 128;
    const int wr = (w >> 1) * 64, wc = (w & 1) * 64;
    const int lr = l & 15, lk = (l >> 4) * 8, lq = (l >> 4) * 4;
    const int srow = l >> 2, scol = (l & 3) * 8;

    f32x4 acc[4][4] = {};
    const u16* Ag = &A [(size_t)(bm + w * 32 + srow) * K + scol];
    const u16* Bg = &Wt[(size_t)(bn + w * 32 + srow) * K + scol];
    u16* Al = &As[(w * 32) * 32];
    u16* Bl = &Bs[(w * 32) * 32];

    for (int k0 = 0; k0 < K; k0 += 32) {
        gload16(Ag + k0,                  Al);
        gload16(Ag + k0 + (size_t)16 * K, Al + 16 * 32);
        gload16(Bg + k0,                  Bl);
        gload16(Bg + k0 + (size_t)16 * K, Bl + 16 * 32);
        __syncthreads();

        bf16x8 af[4], bfr[4];
#pragma unroll
        for (int m = 0; m < 4; ++m) af[m]  = *(const bf16x8*)&As[(wr + m*16 + lr) * 32 + lk];
#pragma unroll
        for (int n = 0; n < 4; ++n) bfr[n] = *(const bf16x8*)&Bs[(wc + n*16 + lr) * 32 + lk];
#pragma unroll
        for (int m = 0; m < 4; ++m)
#pragma unroll
            for (int n = 0; n < 4; ++n)
                acc[m][n] = MFMA16(af[m], bfr[n], acc[m][n]);
        __syncthreads();
    }

    // C/D layout: col=lane&15, row=(lane>>4)*4+j
#pragma unroll
    for (int n = 0; n < 4; ++n) {
        const int col = bn + wc + n*16 + lr;
        const float bv = bias[col];
#pragma unroll
        for (int m = 0; m < 4; ++m) {
#pragma unroll
            for (int j = 0; j < 4; ++j) {
                const int row = bm + wr + m*16 + lq + j;
                float v = acc[m][n][j] + bv;
                if (EPI == 1) v = fmaxf(v, 0.f);
                if (EPI == 2) v += pe[(row % SS) * DD + col];
                if (OF32)  Cf[(size_t)row * N + col] = v;
                if (OBF16) Cb[(size_t)row * N + col] = f2bf(v);
            }
        }
    }
}

// ---------------------------------------------------------------------------
// Fused GEMM + bias + residual + LayerNorm:
//   y = LN(resid + A @ Wt^T + bias) * g + be   -> h (fp32) and hb (bf16)
// Tile 64 rows x 256 cols (full row => LN in-block). 2x2 waves (32x128 each).
// ---------------------------------------------------------------------------
__global__ __launch_bounds__(256)
void gemm_ln(const u16* __restrict__ A, const u16* __restrict__ Wt,
             const float* __restrict__ bias, const float* __restrict__ g,
             const float* __restrict__ be, float* __restrict__ h,
             u16* __restrict__ hb, int K) {
    __shared__ u16 As[64 * 32];
    __shared__ u16 Bs[256 * 32];
    __shared__ float red[64][4];   // [row][wc*2 + {s1,s2}]
    const int t = threadIdx.x, w = t >> 6, l = t & 63;
    const int bm = blockIdx.x * 64;
    const int wr = (w >> 1), wc = (w & 1);
    const int lr = l & 15, lk = (l >> 4) * 8, lq = (l >> 4) * 4;
    const int srow = l >> 2, scol = (l & 3) * 8;

    f32x4 acc[2][8] = {};
    const u16* Ag = &A [(size_t)(bm + w * 16 + srow) * K + scol];
    const u16* Bg = &Wt[(size_t)(w * 64 + srow) * K + scol];
    u16* Al = &As[(w * 16) * 32];
    u16* Bl = &Bs[(w * 64) * 32];

    for (int k0 = 0; k0 < K; k0 += 32) {
        gload16(Ag + k0,                  Al);
        gload16(Bg + k0,                  Bl);
        gload16(Bg + k0 + (size_t)16 * K, Bl + 16 * 32);
        gload16(Bg + k0 + (size_t)32 * K, Bl + 32 * 32);
        gload16(Bg + k0 + (size_t)48 * K, Bl + 48 * 32);
        __syncthreads();

        bf16x8 af[2], bf[8];
#pragma unroll
        for (int mf = 0; mf < 2; ++mf) af[mf] = *(const bf16x8*)&As[(wr*32 + mf*16 + lr) * 32 + lk];
#pragma unroll
        for (int n = 0; n < 8; ++n)    bf[n]  = *(const bf16x8*)&Bs[(wc*128 + n*16 + lr) * 32 + lk];
#pragma unroll
        for (int mf = 0; mf < 2; ++mf)
#pragma unroll
            for (int n = 0; n < 8; ++n)
                acc[mf][n] = MFMA16(af[mf], bf[n], acc[mf][n]);
        __syncthreads();
    }

    float bv[8], gv[8], bev[8];
#pragma unroll
    for (int n = 0; n < 8; ++n) {
        int col = wc*128 + n*16 + lr;
        bv[n] = bias[col]; gv[n] = g[col]; bev[n] = be[col];
    }
    // pass 1: add bias + residual, partial row sums
#pragma unroll
    for (int mf = 0; mf < 2; ++mf) {
#pragma unroll
        for (int j = 0; j < 4; ++j) {
            const int rloc = wr*32 + mf*16 + lq + j;
            const int row  = bm + rloc;
            float s1 = 0.f, s2 = 0.f;
#pragma unroll
            for (int n = 0; n < 8; ++n) {
                float v = acc[mf][n][j] + bv[n] + h[(size_t)row * DD + wc*128 + n*16 + lr];
                acc[mf][n][j] = v;
                s1 += v; s2 += v * v;
            }
            s1 += __shfl_xor(s1, 1); s2 += __shfl_xor(s2, 1);
            s1 += __shfl_xor(s1, 2); s2 += __shfl_xor(s2, 2);
            s1 += __shfl_xor(s1, 4); s2 += __shfl_xor(s2, 4);
            s1 += __shfl_xor(s1, 8); s2 += __shfl_xor(s2, 8);
            if (lr == 0) { red[rloc][wc*2] = s1; red[rloc][wc*2+1] = s2; }
        }
    }
    __syncthreads();
    // pass 2: normalize + store
#pragma unroll
    for (int mf = 0; mf < 2; ++mf) {
#pragma unroll
        for (int j = 0; j < 4; ++j) {
            const int rloc = wr*32 + mf*16 + lq + j;
            const int row  = bm + rloc;
            float s1 = red[rloc][0] + red[rloc][2];
            float s2 = red[rloc][1] + red[rloc][3];
            float mean = s1 * (1.f/DD);
            float var  = s2 * (1.f/DD) - mean*mean;
            float rstd = rsqrtf(var + 1e-5f);
#pragma unroll
            for (int n = 0; n < 8; ++n) {
                int col = wc*128 + n*16 + lr;
                float y = (acc[mf][n][j] - mean) * rstd * gv[n] + bev[n];
                h [(size_t)row * DD + col] = y;
                hb[(size_t)row * DD + col] = f2bf(y);
            }
        }
    }
}

// ---------------------------------------------------------------------------
// MFMA attention: one block per (b,h), 4 waves (wave w owns q-rows 32w..32w+32).
// Q/K frags straight from global (predicated zero past row 100). V transposed
// to LDS via coalesced uint4 loads + register transpose. P->LDS bf16, PV MFMA.
// ---------------------------------------------------------------------------
__global__ __launch_bounds__(256)
void attn_mfma(const u16* __restrict__ qkv, u16* __restrict__ ao) {
    const int b = blockIdx.x >> 3, hh = blockIdx.x & 7;
    const int t = threadIdx.x, w = t >> 6, l = t & 63;
    const int lr = l & 15, lk = (l >> 4) * 8, lq = (l >> 4) * 4;
    __shared__ u16 Vt[32 * 136];          // V^T[d][s], s padded/zeroed to 136
    __shared__ u16 Ps[4][32 * 136];
    const size_t rbase = (size_t)b * SS * 768;
    const int qc = hh * 32, kc = 256 + hh * 32, vc = 512 + hh * 32;

    // V stage: coalesced row loads, transpose in regs -> LDS
    for (int u = t; u < 400; u += 256) {           // 100 rows x 4 chunks of 8
        int s = u >> 2, dp = (u & 3) * 8;
        u16x8 vv = *(const u16x8*)&qkv[rbase + (size_t)s * 768 + vc + dp];
#pragma unroll
        for (int e = 0; e < 8; ++e) Vt[(dp + e) * 136 + s] = vv[e];
    }
    for (int i = t; i < 32 * 36; i += 256) {       // zero pad s=100..135
        int d = i / 36, s2 = 100 + i % 36;
        Vt[d * 136 + s2] = 0;
    }

    // Q fragments direct from global
    u16x8 qz = {0,0,0,0,0,0,0,0};
    u16x8 qfr[2];
#pragma unroll
    for (int m = 0; m < 2; ++m) {
        int r = w * 32 + m * 16 + lr;
        qfr[m] = (r < SS) ? *(const u16x8*)&qkv[rbase + (size_t)r * 768 + qc + lk] : qz;
    }

    // S = Q K^T
    f32x4 sacc[2][7] = {};
#pragma unroll
    for (int n = 0; n < 7; ++n) {
        int r = n * 16 + lr;
        u16x8 kfr = (r < SS) ? *(const u16x8*)&qkv[rbase + (size_t)r * 768 + kc + lk] : qz;
#pragma unroll
        for (int m = 0; m < 2; ++m)
            sacc[m][n] = MFMA16(*(bf16x8*)&qfr[m], *(bf16x8*)&kfr, sacc[m][n]);
    }

    // softmax per row (cols n*16+lr; cols>=100 masked)
#pragma unroll
    for (int m = 0; m < 2; ++m) {
#pragma unroll
        for (int j = 0; j < 4; ++j) {
            float mx = -1e30f;
#pragma unroll
            for (int n = 0; n < 7; ++n) {
                float s = sacc[m][n][j] * INV_SCALE;
                if (n == 6 && lr >= 4) s = -1e30f;
                sacc[m][n][j] = s;
                mx = fmaxf(mx, s);
            }
            mx = fmaxf(mx, __shfl_xor(mx, 1));
            mx = fmaxf(mx, __shfl_xor(mx, 2));
            mx = fmaxf(mx, __shfl_xor(mx, 4));
            mx = fmaxf(mx, __shfl_xor(mx, 8));
            float sum = 0.f;
#pragma unroll
            for (int n = 0; n < 7; ++n) {
                float p = expf(sacc[m][n][j] - mx);
                if (n == 6 && lr >= 4) p = 0.f;
                sacc[m][n][j] = p;
                sum += p;
            }
            sum += __shfl_xor(sum, 1);
            sum += __shfl_xor(sum, 2);
            sum += __shfl_xor(sum, 4);
            sum += __shfl_xor(sum, 8);
            float inv = 1.f / sum;
#pragma unroll
            for (int n = 0; n < 7; ++n) sacc[m][n][j] *= inv;
        }
    }

    // P -> LDS (bf16), wave-private; zero pad cols 112..135
    u16* myP = &Ps[w][0];
    for (int i = l; i < 32 * 24; i += 64) {
        int r = i / 24, c2 = 112 + i % 24;
        myP[r * 136 + c2] = 0;
    }
#pragma unroll
    for (int m = 0; m < 2; ++m)
#pragma unroll
        for (int n = 0; n < 7; ++n)
#pragma unroll
            for (int j = 0; j < 4; ++j)
                myP[(m*16 + lq + j) * 136 + n*16 + lr] = f2bf(sacc[m][n][j]);

    __syncthreads();   // Vt + Ps visible

    // O = P @ V
    f32x4 oacc[2][2] = {};
#pragma unroll
    for (int ks = 0; ks < 4; ++ks) {
        bf16x8 pf[2], vf[2];
#pragma unroll
        for (int m = 0; m < 2; ++m) pf[m] = *(const bf16x8*)&myP[(m*16 + lr) * 136 + ks*32 + lk];
#pragma unroll
        for (int n = 0; n < 2; ++n) vf[n] = *(const bf16x8*)&Vt [(n*16 + lr) * 136 + ks*32 + lk];
#pragma unroll
        for (int m = 0; m < 2; ++m)
#pragma unroll
            for (int n = 0; n < 2; ++n)
                oacc[m][n] = MFMA16(pf[m], vf[n], oacc[m][n]);
    }
#pragma unroll
    for (int m = 0; m < 2; ++m)
#pragma unroll
        for (int j = 0; j < 4; ++j) {
            int s = w*32 + m*16 + lq + j;
            if (s < SS) {
#pragma unroll
                for (int n = 0; n < 2; ++n)
                    ao[((size_t)(b*SS + s)) * DD + hh*32 + n*16 + lr] = f2bf(oacc[m][n][j]);
            }
        }
}

// ---------------------------------------------------------------------------
// Residual add + LayerNorm (fp32) — used only for the final LN now.
// ---------------------------------------------------------------------------
__global__ __launch_bounds__(256)
void add_ln_kernel(const float* __restrict__ h, const float* __restrict__ p,
                   const float* __restrict__ g, const float* __restrict__ be,
                   float* __restrict__ out, u16* __restrict__ outb) {
    const int row = blockIdx.x;
    const int c = threadIdx.x;
    const int idx = row * DD + c;
    float x = h[idx];
    if (p) x += p[idx];

    float s1 = x, s2 = x * x;
#pragma unroll
    for (int o = 32; o > 0; o >>= 1) {
        s1 += __shfl_down(s1, o);
        s2 += __shfl_down(s2, o);
    }
    __shared__ float w1[4], w2[4];
    __shared__ float mean_s, rstd_s;
    const int wid = c >> 6, lane = c & 63;
    if (lane == 0) { w1[wid] = s1; w2[wid] = s2; }
    __syncthreads();
    if (c == 0) {
        float t1 = w1[0] + w1[1] + w1[2] + w1[3];
        float t2 = w2[0] + w2[1] + w2[2] + w2[3];
        float m = t1 * (1.0f / DD);
        float v = t2 * (1.0f / DD) - m * m;
        mean_s = m;
        rstd_s = rsqrtf(v + 1e-5f);
    }
    __syncthreads();
    float y = (x - mean_s) * rstd_s * g[c] + be[c];
    out[idx] = y;
    if (outb) outb[idx] = f2bf(y);
}

// ---------------------------------------------------------------------------
// Output heads (unchanged, passing since R0)
// ---------------------------------------------------------------------------
__global__ __launch_bounds__(128)
void heads_kernel(const float* __restrict__ h,
                  const float* __restrict__ Wr1, const float* __restrict__ br1,
                  const float* __restrict__ Wr2, const float* __restrict__ br2,
                  const float* __restrict__ Wa1, const float* __restrict__ ba1,
                  const float* __restrict__ Wa2, const float* __restrict__ ba2,
                  const float* __restrict__ Wa3, const float* __restrict__ ba3,
                  const float* __restrict__ Wc1, const float* __restrict__ bc1,
                  const float* __restrict__ Wc2, const float* __restrict__ bc2,
                  const float* __restrict__ Wv1, const float* __restrict__ bv1,
                  const float* __restrict__ Wv2, const float* __restrict__ bv2,
                  float* __restrict__ out) {
    const int b = blockIdx.x, t = threadIdx.x;
    __shared__ float hf[DD];
    __shared__ float t1[128];
    __shared__ float t2[64];
    __shared__ float lg[3];
    const int hbase = (b * SS + (SS - 1)) * DD;
    hf[t]       = h[hbase + t];
    hf[t + 128] = h[hbase + t + 128];
    out[1536 + b * DD + t]       = hf[t];
    out[1536 + b * DD + t + 128] = hf[t + 128];
    __syncthreads();

    {
        float acc = br1[t];
        for (int k2 = 0; k2 < DD; ++k2) acc = fmaf(hf[k2], Wr1[k2 * 128 + t], acc);
        t1[t] = fmaxf(acc, 0.f);
    }
    __syncthreads();
    if (t < 3) {
        float a = br2[t];
        for (int k2 = 0; k2 < 128; ++k2) a = fmaf(t1[k2], Wr2[k2 * 3 + t], a);
        lg[t] = a;
    }
    __syncthreads();
    if (t == 0) {
        float m = fmaxf(lg[0], fmaxf(lg[1], lg[2]));
        float e0 = expf(lg[0] - m), e1 = expf(lg[1] - m), e2 = expf(lg[2] - m);
        float inv = 1.0f / (e0 + e1 + e2);
        out[256 + b * 3 + 0] = e0 * inv;
        out[256 + b * 3 + 1] = e1 * inv;
        out[256 + b * 3 + 2] = e2 * inv;
    }
    {
        float acc = ba1[t];
        for (int k2 = 0; k2 < DD; ++k2) acc = fmaf(hf[k2], Wa1[k2 * 128 + t], acc);
        t1[t] = fmaxf(acc, 0.f);
    }
    __syncthreads();
    if (t < 64) {
        float acc = ba2[t];
        for (int k2 = 0; k2 < 128; ++k2) acc = fmaf(t1[k2], Wa2[k2 * 64 + t], acc);
        t2[t] = fmaxf(acc, 0.f);
    }
    __syncthreads();
    if (t == 0) {
        float acc = ba3[0];
        for (int k2 = 0; k2 < 64; ++k2) acc = fmaf(t2[k2], Wa3[k2], acc);
        out[b] = tanhf(acc);
    }
    __syncthreads();
    if (t < 64) {
        float acc = bc1[t];
        for (int k2 = 0; k2 < DD; ++k2) acc = fmaf(hf[k2], Wc1[k2 * 64 + t], acc);
        t2[t] = fmaxf(acc, 0.f);
    }
    __syncthreads();
    if (t == 0) {
        float acc = bc2[0];
        for (int k2 = 0; k2 < 64; ++k2) acc = fmaf(t2[k2], Wc2[k2], acc);
        out[1024 + b] = 1.0f / (1.0f + expf(-acc));
    }
    __syncthreads();
    if (t < 64) {
        float acc = bv1[t];
        for (int k2 = 0; k2 < DD; ++k2) acc = fmaf(hf[k2], Wv1[k2 * 64 + t], acc);
        t2[t] = fmaxf(acc, 0.f);
    }
    __syncthreads();
    if (t == 0) {
        float acc = bv2[0];
        for (int k2 = 0; k2 < 64; ++k2) acc = fmaf(t2[k2], Wv2[k2], acc);
        out[1280 + b] = fmaxf(acc, 0.f);
    }
}

// ---------------------------------------------------------------------------
// Launch
// ---------------------------------------------------------------------------
extern "C" void kernel_launch(void* const* d_in, const int* in_sizes, int n_in,
                              void* d_out, int out_size, void* d_ws, size_t ws_size,
                              hipStream_t stream) {
    const float* x    = (const float*)d_in[0];
    const float* W_in = (const float*)d_in[1];
    const float* b_in = (const float*)d_in[2];
    const float* Wq   = (const float*)d_in[3];
    const float* bq   = (const float*)d_in[4];
    const float* Wk   = (const float*)d_in[5];
    const float* bk   = (const float*)d_in[6];
    const float* Wv   = (const float*)d_in[7];
    const float* bv   = (const float*)d_in[8];
    const float* Wo   = (const float*)d_in[9];
    const float* bo   = (const float*)d_in[10];
    const float* g1   = (const float*)d_in[11];
    const float* be1  = (const float*)d_in[12];
    const float* W1   = (const float*)d_in[13];
    const float* b1   = (const float*)d_in[14];
    const float* W2   = (const float*)d_in[15];
    const float* b2   = (const float*)d_in[16];
    const float* g2   = (const float*)d_in[17];
    const float* be2  = (const float*)d_in[18];
    const float* lnf_g = (const float*)d_in[19];
    const float* lnf_b = (const float*)d_in[20];
    const float* Wr1  = (const float*)d_in[21];
    const float* br1  = (const float*)d_in[22];
    const float* Wr2  = (const float*)d_in[23];
    const float* br2  = (const float*)d_in[24];
    const float* Wa1  = (const float*)d_in[25];
    const float* ba1  = (const float*)d_in[26];
    const float* Wa2  = (const float*)d_in[27];
    const float* ba2  = (const float*)d_in[28];
    const float* Wa3  = (const float*)d_in[29];
    const float* ba3  = (const float*)d_in[30];
    const float* Wc1  = (const float*)d_in[31];
    const float* bc1  = (const float*)d_in[32];
    const float* Wc2  = (const float*)d_in[33];
    const float* bc2  = (const float*)d_in[34];
    const float* Wv1  = (const float*)d_in[35];
    const float* bv1  = (const float*)d_in[36];
    const float* Wv2  = (const float*)d_in[37];
    const float* bv2  = (const float*)d_in[38];
    float* out = (float*)d_out;

    // workspace layout
    char* w8 = (char*)d_ws;
    float* pe   = (float*)w8;  w8 += (size_t)SS * DD * 4;
    float* h    = (float*)w8;  w8 += (size_t)MM * DD * 4;
    float* tmp  = (float*)w8;  w8 += (size_t)MM * DD * 4;   // unused (kept for layout stability)
    u16*   hb   = (u16*)w8;    w8 += (size_t)MM * DD * 2;
    u16*   xb   = (u16*)w8;    w8 += (size_t)MM * DIN * 2;
    u16*   qkvb = (u16*)w8;    w8 += (size_t)MM * 768 * 2;
    u16*   ao   = (u16*)w8;    w8 += (size_t)MM * DD * 2;
    u16*   ffn1b= (u16*)w8;    w8 += (size_t)MM * DFF * 2;
    u16*   WinT = (u16*)w8;    w8 += (size_t)DIN * DD * 2;
    u16*   WqkvT= (u16*)w8;    w8 += (size_t)LL * 768 * DD * 2;
    u16*   WoT  = (u16*)w8;    w8 += (size_t)LL * DD * DD * 2;
    u16*   W1T  = (u16*)w8;    w8 += (size_t)LL * DFF * DD * 2;
    u16*   W2T  = (u16*)w8;    w8 += (size_t)LL * DD * DFF * 2;
    float* bqkv = (float*)w8;  w8 += (size_t)LL * 768 * 4;
    (void)tmp;

    // prep
    pe_init_kernel<<<(SS * DD + 255) / 256, 256, 0, stream>>>(pe);
    conv_bf16<<<(MM * DIN + 255) / 256, 256, 0, stream>>>(x, xb, MM * DIN);
    transpose_conv<<<dim3(DIN/32, DD/32, 1), 256, 0, stream>>>(W_in, WinT, DIN, DD, (long)DIN * DD);
    transpose_conv<<<dim3(8, 8, 6),  256, 0, stream>>>(Wq, WqkvT,             DD, DD, 768L * DD);
    transpose_conv<<<dim3(8, 8, 6),  256, 0, stream>>>(Wk, WqkvT + DD*DD,     DD, DD, 768L * DD);
    transpose_conv<<<dim3(8, 8, 6),  256, 0, stream>>>(Wv, WqkvT + 2*DD*DD,   DD, DD, 768L * DD);
    transpose_conv<<<dim3(8, 8, 6),  256, 0, stream>>>(Wo, WoT, DD, DD, (long)DD * DD);
    transpose_conv<<<dim3(8, 32, 6), 256, 0, stream>>>(W1, W1T, DD, DFF, (long)DD * DFF);
    transpose_conv<<<dim3(32, 8, 6), 256, 0, stream>>>(W2, W2T, DFF, DD, (long)DD * DFF);
    pack_bias<<<(LL * 768 + 255) / 256, 256, 0, stream>>>(bq, bk, bv, bqkv);

    // input projection + PE  (h fp32 + hb bf16)
    mfma_gemm<2, true, true><<<dim3(MM/128, DD/128), 256, 0, stream>>>(
        xb, WinT, b_in, pe, h, hb, MM, DD, DIN);

    for (int l = 0; l < LL; ++l) {
        mfma_gemm<0, false, true><<<dim3(MM/128, 768/128), 256, 0, stream>>>(
            hb, WqkvT + (size_t)l*768*DD, bqkv + l*768, nullptr, nullptr, qkvb, MM, 768, DD);
        attn_mfma<<<BB * HH, 256, 0, stream>>>(qkvb, ao);
        gemm_ln<<<MM/64, 256, 0, stream>>>(
            ao, WoT + (size_t)l*DD*DD, bo + l*DD, g1 + l*DD, be1 + l*DD, h, hb, DD);
        mfma_gemm<1, false, true><<<dim3(MM/128, DFF/128), 256, 0, stream>>>(
            hb, W1T + (size_t)l*DFF*DD, b1 + l*DFF, nullptr, nullptr, ffn1b, MM, DFF, DD);
        gemm_ln<<<MM/64, 256, 0, stream>>>(
            ffn1b, W2T + (size_t)l*DD*DFF, b2 + l*DD, g2 + l*DD, be2 + l*DD, h, hb, DFF);
    }

    // final LN (in place, fp32 only)
    add_ln_kernel<<<MM, DD, 0, stream>>>(h, nullptr, lnf_g, lnf_b, h, nullptr);

    heads_kernel<<<BB, 128, 0, stream>>>(h,
        Wr1, br1, Wr2, br2,
        Wa1, ba1, Wa2, ba2, Wa3, ba3,
        Wc1, bc1, Wc2, bc2,
        Wv1, bv1, Wv2, bv2,
        out);
}